// Round 1
// baseline (1130.837 us; speedup 1.0000x reference)
//
#include <hip/hip_runtime.h>
#include <math.h>

// Problem constants (match reference)
constexpr int B_  = 4096;
constexpr int T_  = 200;
constexpr int D_  = 64;
constexpr int H1_ = 80;
constexpr int H2_ = 40;
constexpr int NT  = 256;               // threads per block
constexpr float NEG_INF_F = -4294967295.0f;  // float32(-2^32+1) -> rounds same as jnp

// ---------------------------------------------------------------------------
// Pre-kernel: fold W1 and transpose W2 into workspace.
// wf layout: [c=0..7][n=0..79][16] where per (c,n):
//   j in 0..7  : Wk [d=c*8+j][n] = W1[(64+d)*80+n] - W1[(128+d)*80+n]
//   j in 8..15 : Wqk[d=c*8+j-8][n] = W1[(192+d)*80+n]
// w2t layout: [m=0..39][n=0..79] = W2[n][m]
// ---------------------------------------------------------------------------
__global__ void fold_weights(const float* __restrict__ W1,
                             const float* __restrict__ W2,
                             float* __restrict__ wf,
                             float* __restrict__ w2t) {
    int i = blockIdx.x * blockDim.x + threadIdx.x;
    const int total1 = 8 * 80 * 16;  // 10240
    if (i < total1) {
        int j = i & 15;
        int n = (i >> 4) % 80;
        int c = i / (16 * 80);
        int d = c * 8 + (j & 7);
        float v;
        if (j < 8) v = W1[(64 + d) * 80 + n] - W1[(128 + d) * 80 + n];
        else       v = W1[(192 + d) * 80 + n];
        wf[i] = v;
    }
    int i2 = i - total1;
    if (i2 >= 0 && i2 < 40 * 80) {
        int n = i2 % 80;
        int m = i2 / 80;
        w2t[i2] = W2[n * 40 + m];
    }
}

// ---------------------------------------------------------------------------
// Main kernel: one block per batch row b; thread t handles key position t.
// ---------------------------------------------------------------------------
__global__ __launch_bounds__(NT)
void din_attn(const float* __restrict__ q,
              const float* __restrict__ keys,
              const int*   __restrict__ klen,
              const float* __restrict__ W1,
              const float* __restrict__ b1,
              const float* __restrict__ w2t,
              const float* __restrict__ b2,
              const float* __restrict__ W3,
              const float* __restrict__ b3,
              const float* __restrict__ wf,
              float* __restrict__ out) {
    const int b   = blockIdx.x;
    const int tid = threadIdx.x;

    __shared__ float qs[D_];
    __shared__ float hinit[H1_];
    __shared__ float red[NT];        // logits, then attn weights
    __shared__ float part[4][D_];
    __shared__ float wred[8];

    if (tid < D_) qs[tid] = q[b * D_ + tid];
    __syncthreads();

    // hinit[n] = b1[n] + sum_d q[d] * (W1[d][n] + W1[128+d][n])   (t-invariant)
    if (tid < H1_) {
        float acc = b1[tid];
        #pragma unroll 8
        for (int d = 0; d < D_; ++d)
            acc = fmaf(qs[d], W1[d * 80 + tid] + W1[(128 + d) * 80 + tid], acc);
        hinit[tid] = acc;
    }
    __syncthreads();

    const int len = klen[b];
    const int t = tid;
    if (t < T_) {
        float h[H1_];
        #pragma unroll
        for (int n = 0; n < H1_; ++n) h[n] = hinit[n];

        const float* kr = keys + ((size_t)b * T_ + t) * D_;
        #pragma unroll 1
        for (int c = 0; c < 8; ++c) {
            float kv[8], qk[8];
            float4 a0 = *(const float4*)(kr + c * 8);
            float4 a1 = *(const float4*)(kr + c * 8 + 4);
            kv[0] = a0.x; kv[1] = a0.y; kv[2] = a0.z; kv[3] = a0.w;
            kv[4] = a1.x; kv[5] = a1.y; kv[6] = a1.z; kv[7] = a1.w;
            #pragma unroll
            for (int j = 0; j < 8; ++j) qk[j] = kv[j] * qs[c * 8 + j];

            const float* w = wf + c * 80 * 16;
            #pragma unroll
            for (int n = 0; n < H1_; ++n) {
                float acc = h[n];
                #pragma unroll
                for (int j = 0; j < 8; ++j) acc = fmaf(kv[j], w[n * 16 + j], acc);
                #pragma unroll
                for (int j = 0; j < 8; ++j) acc = fmaf(qk[j], w[n * 16 + 8 + j], acc);
                h[n] = acc;
            }
        }
        // sigmoid layer 1 (in place)
        #pragma unroll
        for (int n = 0; n < H1_; ++n) h[n] = 1.0f / (1.0f + __expf(-h[n]));

        // layers 2+3 fused: logit = b3 + sum_m sigmoid(b2[m] + h.W2t[m]) * W3[m]
        float logit = b3[0];
        #pragma unroll 1
        for (int m = 0; m < H2_; ++m) {
            float acc = b2[m];
            const float* w2 = w2t + m * 80;
            #pragma unroll
            for (int n = 0; n < H1_; ++n) acc = fmaf(h[n], w2[n], acc);
            float s = 1.0f / (1.0f + __expf(-acc));
            logit = fmaf(s, W3[m], logit);
        }

        float l = (t < len) ? logit : NEG_INF_F;
        red[t] = l * 0.125f;   // 1/sqrt(64)
    } else {
        red[t] = -INFINITY;    // padding rows: excluded (exp -> 0)
    }
    __syncthreads();

    // block-wide softmax over red[0..255]
    float v = red[tid];
    float m = v;
    #pragma unroll
    for (int off = 32; off; off >>= 1) m = fmaxf(m, __shfl_xor(m, off));
    if ((tid & 63) == 0) wred[tid >> 6] = m;
    __syncthreads();
    m = fmaxf(fmaxf(wred[0], wred[1]), fmaxf(wred[2], wred[3]));
    float e = __expf(v - m);   // v=-inf -> 0; all-masked row -> exp(0)=1 (uniform)
    float s = e;
    #pragma unroll
    for (int off = 32; off; off >>= 1) s += __shfl_xor(s, off);
    if ((tid & 63) == 0) wred[4 + (tid >> 6)] = s;
    __syncthreads();
    s = wred[4] + wred[5] + wred[6] + wred[7];
    red[tid] = e / s;          // attn weight (t >= 200 -> 0)
    __syncthreads();

    // out[b][d] = sum_t attn[t] * keys[b][t][d]
    {
        const int d = tid & 63, g = tid >> 6;
        float acc = 0.f;
        const float* kb = keys + (size_t)b * T_ * D_;
        for (int tt = g; tt < T_; tt += 4)
            acc = fmaf(red[tt], kb[tt * D_ + d], acc);
        part[g][d] = acc;
        __syncthreads();
        if (tid < D_)
            out[b * D_ + tid] = part[0][tid] + part[1][tid] + part[2][tid] + part[3][tid];
    }
}

extern "C" void kernel_launch(void* const* d_in, const int* in_sizes, int n_in,
                              void* d_out, int out_size, void* d_ws, size_t ws_size,
                              hipStream_t stream) {
    const float* q    = (const float*)d_in[0];
    const float* keys = (const float*)d_in[1];
    const int*   kl   = (const int*)d_in[2];
    const float* W1   = (const float*)d_in[3];
    const float* b1   = (const float*)d_in[4];
    const float* W2   = (const float*)d_in[5];
    const float* b2   = (const float*)d_in[6];
    const float* W3   = (const float*)d_in[7];
    const float* b3   = (const float*)d_in[8];

    float* wf  = (float*)d_ws;       // 10240 floats (40 KB)
    float* w2t = wf + 10240;         // 3200 floats  (12.8 KB)

    fold_weights<<<(13440 + 255) / 256, 256, 0, stream>>>(W1, W2, wf, w2t);
    din_attn<<<B_, NT, 0, stream>>>(q, keys, kl, W1, b1, w2t, b2, W3, b3, wf,
                                    (float*)d_out);
}